// Round 9
// baseline (128.218 us; speedup 1.0000x reference)
//
#include <hip/hip_runtime.h>
#include <hip/hip_bf16.h>

#define BN 8192
#define DIM 512
#define NB  64            // BN / 128 block-rows
#define NTILES 2080       // NB*(NB+1)/2 upper-triangle tiles
#define EPSF 1e-8f

using v8i   = __attribute__((ext_vector_type(8))) int;
using v4i   = __attribute__((ext_vector_type(4))) int;
using f32x4 = __attribute__((ext_vector_type(4))) float;
using f32x2 = __attribute__((ext_vector_type(2))) float;

// Native exp2 (single v_exp_f32); fallback keeps exact semantics.
#if __has_builtin(__builtin_amdgcn_exp2f)
#define EXP2F(x) __builtin_amdgcn_exp2f(x)
#else
#define EXP2F(x) __expf((x) * 0.69314718055994531f)
#endif

__device__ __forceinline__ f32x2 shfl_xor2(f32x2 v, int m) {
    f32x2 r;
    r[0] = __shfl_xor(v[0], m, 64);
    r[1] = __shfl_xor(v[1], m, 64);
    return r;
}

// Async global->LDS, 16 B per lane, dest = uniform base + lane*16.
__device__ __forceinline__ void async_copy16(const void* g, void* l) {
    __builtin_amdgcn_global_load_lds(
        (const __attribute__((address_space(1))) void*)g,
        (__attribute__((address_space(3))) void*)l,
        16, 0, 0);
}

// One wave per row: L2-normalize, x4 pre-scale, fp8 e4m3. Block 0 zeroes
// out[0] and cntG; every block zeroes its 4 rows of the collapsed P/N
// accumulators (gemm atomically accumulates into them; stream-ordered).
__global__ __launch_bounds__(256) void normalize_kernel(
        const float* __restrict__ emb, unsigned char* __restrict__ E,
        int* __restrict__ cntG, float* __restrict__ P, float* __restrict__ N,
        float* __restrict__ out) {
    if (blockIdx.x == 0) {
        if (threadIdx.x == 0) out[0] = 0.f;
        if (threadIdx.x < 128) cntG[threadIdx.x] = 0;
    }
    int lane = threadIdx.x & 63;
    int row  = blockIdx.x * 4 + (threadIdx.x >> 6);
    if (lane == 0) { P[row] = 0.f; N[row] = 0.f; }
    const float4* src = (const float4*)(emb + (size_t)row * DIM);
    float4 a = src[lane];
    float4 b = src[lane + 64];
    float ss = a.x*a.x + a.y*a.y + a.z*a.z + a.w*a.w
             + b.x*b.x + b.y*b.y + b.z*b.z + b.w*b.w;
    #pragma unroll
    for (int m = 1; m < 64; m <<= 1) ss += __shfl_xor(ss, m, 64);
    float s4 = 4.0f / fmaxf(sqrtf(ss), 1e-12f);
    int pa = __builtin_amdgcn_cvt_pk_fp8_f32(a.x*s4, a.y*s4, 0, false);
    pa     = __builtin_amdgcn_cvt_pk_fp8_f32(a.z*s4, a.w*s4, pa, true);
    int pb = __builtin_amdgcn_cvt_pk_fp8_f32(b.x*s4, b.y*s4, 0, false);
    pb     = __builtin_amdgcn_cvt_pk_fp8_f32(b.z*s4, b.w*s4, pb, true);
    unsigned char* rowp = E + (size_t)row * DIM;
    ((unsigned*)rowp)[lane]         = (unsigned)pa;
    ((unsigned*)(rowp + 256))[lane] = (unsigned)pb;
}

// Upper-triangle 128x128 tiles, 1D grid (2080), triangular decode.
// fp8 MX MFMA 16x16x128. 512-thread blocks (8 waves), wave (vC,vQ) owns a
// 64x32 output. Round-6 proven front half: whole-tile A staging (4 planes,
// 64 KB), ONE barrier (counted vmcnt(4)), barrier-free k-loop with B
// register-double-buffered.
// NEW (round 9): the entire back half of the per-block serial chain is
// gone. Per-wave in-register shfl_xor butterfly reduces row sums (proven
// numerics, r2/r3), then waves atomicAdd directly into collapsed P[8192]/
// N[8192]. No epilogue __syncthreads, no rowBuf/colBuf LDS, no 16 MB P/N
// store traffic; after the prologue barrier every wave runs to retirement
// independently -- the phase-correlated no-issue time (58% of cycles,
// invariant across r4-r8 occupancy changes) is what this attacks.
__global__ __launch_bounds__(512, 4) void gemm_epi_kernel(
        const unsigned char* __restrict__ E, const int* __restrict__ labels,
        int* __restrict__ cntG, float* __restrict__ P, float* __restrict__ N) {
    __shared__ __attribute__((aligned(16))) unsigned char As[65536];
    __shared__ int labI[128];
    __shared__ int labJ[128];

    int t  = blockIdx.x;
    int bi = (int)(64.5f - sqrtf(64.5f * 64.5f - 2.0f * (float)t));
    while (64 * (bi + 1) - ((bi + 1) * bi) / 2 <= t) ++bi;
    while (64 * bi - (bi * (bi - 1)) / 2 > t) --bi;
    int bj = bi + (t - (64 * bi - (bi * (bi - 1)) / 2));
    const bool diag = (bi == bj);
    const int i0 = bi * 128;
    const int j0 = bj * 128;

    const int tid  = threadIdx.x;
    const int wave = tid >> 6;          // 0..7
    const int lane = tid & 63;
    const int quad = lane >> 4;
    const int lrow = lane & 15;
    const int vC   = wave >> 2;         // i-half   (0..1)
    const int vQ   = wave & 3;          // j-quarter(0..3)
    const int i_w  = vC * 64;
    const int j_w  = vQ * 32;

    if (tid < 128)        labI[tid]       = labels[i0 + tid];
    else if (tid < 256)   labJ[tid - 128] = labels[j0 + tid - 128];
    // Diag blocks build the global label histogram (64 blocks x 128 rows
    // covers every row exactly once). Retired by the prologue vmcnt.
    if (diag && tid < 128) atomicAdd(&cntG[labels[i0 + tid]], 1);

    f32x4 acc[4][2];
    #pragma unroll
    for (int a = 0; a < 4; ++a)
        #pragma unroll
        for (int b = 0; b < 2; ++b)
            acc[a][b] = (f32x4){0.f, 0.f, 0.f, 0.f};

    const v4i* bptr[2];
    #pragma unroll
    for (int tj = 0; tj < 2; ++tj)
        bptr[tj] = (const v4i*)(E +
            (size_t)(j0 + j_w + tj * 16 + lrow) * DIM + quad * 32);

    // Staging lane constants: each wave covers rows [wave*16, wave*16+16),
    // 2 instrs x 8 rows per plane; lane l -> row (l>>3), LDS chunk l&7
    // holds global chunk (l&7)^(l>>3) (row&7 == l>>3, bases multiple of 8).
    const int stRow = lane >> 3;
    const int stChk = (lane & 7) ^ stRow;
    const unsigned char* gA = E + (size_t)(i0 + wave * 16 + stRow) * DIM
                                + stChk * 16;
    const int sw = lrow & 7;

    // Prologue: stage ALL 4 A-planes (8 instrs/wave), then B(0) prefetch
    // (4). vmcnt(4): staging (and the diag atomic) retired, B0 still in
    // flight. lgkmcnt(0) drains the label ds_writes.
    #pragma unroll
    for (int c = 0; c < 4; ++c)
        #pragma unroll
        for (int h = 0; h < 2; ++h)
            async_copy16(gA + (size_t)h * 8 * DIM + c * 128,
                         As + (size_t)c * 16384
                            + (size_t)(wave * 16 + h * 8) * 128);
    __builtin_amdgcn_sched_barrier(0);   // keep staging before B loads

    v8i bf[2][2];
    #pragma unroll
    for (int tj = 0; tj < 2; ++tj) {      // prefetch B for k=0
        ((v4i*)&bf[0][tj])[0] = bptr[tj][0];
        ((v4i*)&bf[0][tj])[1] = bptr[tj][1];
    }
    asm volatile("s_waitcnt vmcnt(4) lgkmcnt(0)" ::: "memory");
    __builtin_amdgcn_s_barrier();
    // ---- from here to kernel end: NO block-wide syncs at all ----

    #pragma unroll
    for (int k = 0; k < 4; ++k) {
        const int cur = k & 1;
        const unsigned char* bufC = As + (size_t)k * 16384;
        v8i af[4];
        #pragma unroll
        for (int ti = 0; ti < 4; ++ti) {
            int r  = i_w + ti * 16 + lrow;
            const v4i* rp = (const v4i*)(bufC + (size_t)r * 128);
            ((v4i*)&af[ti])[0] = rp[(quad * 2) ^ sw];
            ((v4i*)&af[ti])[1] = rp[(quad * 2 + 1) ^ sw];
        }
        if (k < 3) {                      // prefetch next k's B
            #pragma unroll
            for (int tj = 0; tj < 2; ++tj) {
                ((v4i*)&bf[cur ^ 1][tj])[0] = bptr[tj][(k + 1) * 8];
                ((v4i*)&bf[cur ^ 1][tj])[1] = bptr[tj][(k + 1) * 8 + 1];
            }
        }
        #pragma unroll
        for (int ti = 0; ti < 4; ++ti)
            #pragma unroll
            for (int tj = 0; tj < 2; ++tj)
                acc[ti][tj] =
                    __builtin_amdgcn_mfma_scale_f32_16x16x128_f8f6f4(
                        af[ti], bf[cur][tj], acc[ti][tj],
                        0, 0,                 // fp8 e4m3 / e4m3
                        0, 0x7F7F7F7F,        // A scale = 1.0
                        0, 0x7F7F7F7F);       // B scale = 1.0
    }

    // Epilogue, fully per-wave. C/D: col = lane&15, row = quad*4 + reg.
    // acc = 16*S; w = exp(S-1) = exp2(acc*K1 + K2). 32 elements/thread.
    // Row sums: 4-step shfl_xor butterfly over the 16 lrow lanes (r2/r3
    // proven); col sums: 2-step reduce over quads. Results atomicAdd'ed
    // into collapsed P[BN]/N[BN].
    const float K1 = 0.0901619783824569f;    // log2(e)/16
    const float K2 = -1.4426950408889634f;   // -log2(e)
    const bool b0 = (lrow & 1) != 0;
    const bool b1 = (lrow & 2) != 0;

    f32x2 csum[2];
    csum[0] = (f32x2){0.f, 0.f};
    csum[1] = (f32x2){0.f, 0.f};

    #pragma unroll
    for (int ti = 0; ti < 4; ++ti) {
        f32x2 pn[4];
        #pragma unroll
        for (int reg = 0; reg < 4; ++reg) {
            int irow = i_w + ti * 16 + quad * 4 + reg;
            int li   = labI[irow];
            float pos = 0.f, ts = 0.f, sf = 0.f;
            #pragma unroll
            for (int tj = 0; tj < 2; ++tj) {
                int jcol = j_w + tj * 16 + lrow;
                float w  = EXP2F(fmaf(acc[ti][tj][reg], K1, K2));
                float ws = (li == labJ[jcol]) ? w : 0.f;
                pos += ws;  ts += w;
                if (diag) sf += (irow == jcol) ? w : 0.f;
                csum[tj][0] += ws;
                csum[tj][1] += w;
            }
            pn[reg] = (f32x2){pos - sf, ts - pos};   // (pos excl self, neg)
        }
        // Butterfly: step A (mask 1) combines reg pairs {0,1},{2,3};
        // keep reg bit0 == b0. Step B (mask 2): keep reg bit1 == b1.
        f32x2 s01 = b0 ? pn[0] : pn[1];
        f32x2 q0  = (b0 ? pn[1] : pn[0]) + shfl_xor2(s01, 1);
        f32x2 s23 = b0 ? pn[2] : pn[3];
        f32x2 q1  = (b0 ? pn[3] : pn[2]) + shfl_xor2(s23, 1);
        f32x2 sB = b1 ? q0 : q1;
        f32x2 v  = (b1 ? q1 : q0) + shfl_xor2(sB, 2);
        v += shfl_xor2(v, 4);
        v += shfl_xor2(v, 8);
        // lane holds full 32-col sum for row = i_w+ti*16+quad*4+(lrow&3),
        // duplicated over lrow>>2.
        if (lrow < 4) {
            int irow = i_w + ti * 16 + quad * 4 + lrow;
            atomicAdd(&P[i0 + irow], v[0]);
            atomicAdd(&N[i0 + irow], v[1]);
        }
    }

    if (!diag) {
        #pragma unroll
        for (int tj = 0; tj < 2; ++tj) {
            f32x2 cv = csum[tj];
            cv += shfl_xor2(cv, 16);
            cv += shfl_xor2(cv, 32);
            if (quad == 0) {
                int jcol = j_w + tj * 16 + lrow;
                atomicAdd(&P[j0 + jcol], cv[0]);
                atomicAdd(&N[j0 + jcol], cv[1] - cv[0]);
            }
        }
    }
}

// Trivial tail: 32 blocks x 256, one row per thread from the collapsed
// P/N accumulators; per-row loss, wave+LDS reduce, one atomicAdd/block.
__global__ __launch_bounds__(256) void reduce_finalize_kernel(
        const int* __restrict__ labels, const float* __restrict__ P,
        const float* __restrict__ N, const int* __restrict__ cntG,
        float* __restrict__ out) {
    __shared__ float wsum[4];
    int tid = threadIdx.x;
    int i = blockIdx.x * 256 + tid;
    float p = P[i];
    float n = N[i];
    int   cl = cntG[labels[i]];
    float pm = p / fmaxf((float)(cl - 1), 1.0f);
    float nm = n / fmaxf((float)(BN - cl), 1.0f);
    float v  = ((cl - 1 > 0) && (BN - cl > 0))
                   ? -logf(pm / (pm + nm + EPSF)) : 0.0f;
    v *= (1.0f / (float)BN);
    #pragma unroll
    for (int m = 1; m < 64; m <<= 1) v += __shfl_xor(v, m, 64);
    if ((tid & 63) == 0) wsum[tid >> 6] = v;
    __syncthreads();
    if (tid == 0)
        atomicAdd(out, wsum[0] + wsum[1] + wsum[2] + wsum[3]);
}

extern "C" void kernel_launch(void* const* d_in, const int* in_sizes, int n_in,
                              void* d_out, int out_size, void* d_ws, size_t ws_size,
                              hipStream_t stream) {
    const float* emb   = (const float*)d_in[0];
    const int* labels  = (const int*)d_in[1];
    float* out         = (float*)d_out;

    // ws layout: E (8 MB reserved; fp8 uses 4, cnt lives at +4 MB) |
    // P (32 KB) | N (32 KB)   (collapsed accumulators)
    unsigned char* E   = (unsigned char*)d_ws;
    int* cntG          = (int*)((char*)d_ws + (size_t)BN * DIM);
    float* P           = (float*)((char*)d_ws + (size_t)BN * DIM * 2);
    float* N           = P + BN;

    normalize_kernel<<<BN / 4, 256, 0, stream>>>(emb, E, cntG, P, N, out);
    gemm_epi_kernel<<<NTILES, 512, 0, stream>>>(E, labels, cntG, P, N);
    reduce_finalize_kernel<<<32, 256, 0, stream>>>(labels, P, N, cntG, out);
}